// Round 1
// baseline (542.991 us; speedup 1.0000x reference)
//
#include <hip/hip_runtime.h>

#define BATCH 8
#define HH 2048
#define WW 2048
#define NPIX (HH*WW)
#define TOPK 8192
#define NB 16384
#define PEAK_CAP 262144
#define CAND_CAP 16384

// workspace byte offsets
#define OFF_PEAKS  0ull
#define OFF_CANDS  (OFF_PEAKS + (size_t)BATCH*PEAK_CAP*8ull)   // 16 MB
#define OFF_HIST   (OFF_CANDS + (size_t)BATCH*CAND_CAP*8ull)   // +1 MB
#define OFF_SA     (OFF_HIST  + (size_t)BATCH*NB*4ull)
#define OFF_FILL   (OFF_SA    + (size_t)BATCH*NB*4ull)
#define OFF_PCOUNT (OFF_FILL  + (size_t)BATCH*NB*4ull)
#define OFF_END    (OFF_PCOUNT + 64ull + 64ull + 64ull)
#define OFF_NCAND  (OFF_PCOUNT + 64ull)
#define OFF_BSTAR  (OFF_NCAND + 64ull)

__device__ __forceinline__ int bucket_of(float v) {
    int bk = (int)(v * 16384.0f);
    if (bk > NB - 1) bk = NB - 1;
    if (bk < 0) bk = 0;
    return bk;
}

// ---------------- K1: NMS + peak collection + value histogram ----------------
// block: 256 threads; each thread: 4 consecutive cols x 8 rows.
// grid: (2, 256, 8)
__global__ __launch_bounds__(256) void k_nms(
    const float* __restrict__ scores,
    unsigned long long* __restrict__ peaks,
    unsigned int* __restrict__ hist,
    unsigned int* __restrict__ pcount)
{
    const int b = blockIdx.z;
    const int x = (blockIdx.x * 256 + threadIdx.x) * 4;
    const int ybase = blockIdx.y * 8;
    const float* img = scores + (size_t)b * NPIX;

    __shared__ unsigned long long lbuf[1024];
    __shared__ unsigned int lcnt;
    __shared__ unsigned int lbase;
    if (threadIdx.x == 0) lcnt = 0;
    __syncthreads();

    float hmax[12][4];  // sliding horizontal 5-max per loaded row
    float cen[8][4];    // center values for the 8 output rows

    const int i0 = (x >= 4) ? ((x - 4) >> 2) : 0;
    const int i1 = x >> 2;
    const int i2 = (x + 4 <= WW - 4) ? ((x + 4) >> 2) : (WW / 4 - 1);

#pragma unroll
    for (int j = 0; j < 12; ++j) {
        int yy = ybase + j - 2;
        yy = yy < 0 ? 0 : (yy > HH - 1 ? HH - 1 : yy);
        const float4* row = (const float4*)(img + (size_t)yy * WW);
        float4 a = row[i0], bq = row[i1], cq = row[i2];
        float v[12] = {a.x, a.y, a.z, a.w, bq.x, bq.y, bq.z, bq.w, cq.x, cq.y, cq.z, cq.w};
        float aa[7];
#pragma unroll
        for (int i = 0; i < 7; ++i) aa[i] = fmaxf(v[i + 2], v[i + 3]);
        float bb[5];
#pragma unroll
        for (int i = 0; i < 5; ++i) bb[i] = fmaxf(aa[i], aa[i + 2]);   // max v[i+2..i+5]
#pragma unroll
        for (int i = 0; i < 4; ++i) hmax[j][i] = fmaxf(bb[i], v[i + 6]); // max v[i+2..i+6]
        if (j >= 2 && j <= 9) {
#pragma unroll
            for (int i = 0; i < 4; ++i) cen[j - 2][i] = v[4 + i];
        }
    }

#pragma unroll
    for (int o = 0; o < 8; ++o) {
        const int yy = ybase + o;
        const bool yok = (yy >= 2) && (yy <= HH - 3);
#pragma unroll
        for (int i = 0; i < 4; ++i) {
            float xm = fmaxf(fmaxf(fmaxf(hmax[o][i], hmax[o + 1][i]),
                                   fmaxf(hmax[o + 2][i], hmax[o + 3][i])),
                             hmax[o + 4][i]);
            const int col = x + i;
            bool pk = yok && (col >= 2) && (col <= WW - 3) && (cen[o][i] == xm);
            if (pk) {
                unsigned int pos = atomicAdd(&lcnt, 1u);
                if (pos < 1024u) {
                    unsigned int idx = (unsigned int)(yy * WW + col);
                    unsigned int vb = __float_as_uint(cen[o][i]);
                    lbuf[pos] = ((unsigned long long)vb << 32) | (unsigned long long)(~idx);
                }
            }
        }
    }
    __syncthreads();
    unsigned int cnt = lcnt;
    if (cnt > 1024u) cnt = 1024u;
    if (threadIdx.x == 0) lbase = atomicAdd(&pcount[b], cnt);
    __syncthreads();
    const unsigned int gbase = lbase;
    for (unsigned int s = threadIdx.x; s < cnt; s += 256) {
        unsigned long long key = lbuf[s];
        unsigned int gpos = gbase + s;
        if (gpos < PEAK_CAP) {
            peaks[(size_t)b * PEAK_CAP + gpos] = key;
            float v = __uint_as_float((unsigned int)(key >> 32));
            atomicAdd(&hist[b * NB + bucket_of(v)], 1u);
        }
    }
}

// ---------------- K2: per-batch suffix scan of histogram, find B* ----------------
// grid: (8), block 256
__global__ __launch_bounds__(256) void k_scan(
    const unsigned int* __restrict__ hist,
    unsigned int* __restrict__ SA,
    unsigned int* __restrict__ ncand,
    unsigned int* __restrict__ bstar)
{
    const int b = blockIdx.x;
    const unsigned int* hb = hist + b * NB;
    unsigned int* sab = SA + b * NB;
    const int t = threadIdx.x;

    __shared__ unsigned int ps[256];
    __shared__ int bmax;

    unsigned int sum = 0;
    for (int i = 0; i < 64; ++i) sum += hb[t * 64 + i];
    ps[t] = sum;
    __syncthreads();
    // inclusive suffix scan over the 256 chunk sums
    for (int off = 1; off < 256; off <<= 1) {
        unsigned int v = (t + off < 256) ? ps[t + off] : 0u;
        __syncthreads();
        ps[t] += v;
        __syncthreads();
    }
    unsigned int run = ps[t] - sum;  // strictly above this chunk
    int bst_local = -1;
    for (int i = 63; i >= 0; --i) {
        int bin = t * 64 + i;
        unsigned int hv = hb[bin];
        sab[bin] = run;
        if (run + hv >= TOPK && bst_local < 0) bst_local = bin;
        run += hv;
    }
    if (t == 0) bmax = -1;
    __syncthreads();
    if (bst_local >= 0) atomicMax(&bmax, bst_local);
    __syncthreads();
    if (t == 0) {
        int Bs = bmax < 0 ? 0 : bmax;
        bstar[b] = (unsigned int)Bs;
        unsigned int n = sab[Bs] + hb[Bs];
        if (n > CAND_CAP) n = CAND_CAP;
        ncand[b] = n;
    }
}

// ---------------- K3: filter peaks above threshold into bucket-grouped cands ----------------
// grid: (1024, 8), block 256
__global__ __launch_bounds__(256) void k_filter(
    const unsigned long long* __restrict__ peaks,
    const unsigned int* __restrict__ pcount,
    const unsigned int* __restrict__ bstar,
    const unsigned int* __restrict__ SA,
    unsigned int* __restrict__ fill,
    unsigned long long* __restrict__ cands)
{
    const int b = blockIdx.y;
    unsigned int n = pcount[b];
    if (n > PEAK_CAP) n = PEAK_CAP;
    unsigned int i = blockIdx.x * 256 + threadIdx.x;
    if (i >= n) return;
    unsigned long long key = peaks[(size_t)b * PEAK_CAP + i];
    float v = __uint_as_float((unsigned int)(key >> 32));
    int bk = bucket_of(v);
    if ((unsigned int)bk < bstar[b]) return;
    unsigned int pos = SA[b * NB + bk] + atomicAdd(&fill[b * NB + bk], 1u);
    if (pos < CAND_CAP) cands[(size_t)b * CAND_CAP + pos] = key;
}

// ---------------- K4: exact rank within bucket + per-keypoint outputs ----------------
// grid: (64, 8), block 256
__global__ __launch_bounds__(256) void k_out(
    const float* __restrict__ scores,
    const unsigned long long* __restrict__ cands,
    const unsigned int* __restrict__ ncand,
    const unsigned int* __restrict__ SA,
    const unsigned int* __restrict__ hist,
    float* __restrict__ out)
{
    const int b = blockIdx.y;
    unsigned int n = ncand[b];
    if (n > CAND_CAP) n = CAND_CAP;
    unsigned int ci = blockIdx.x * 256 + threadIdx.x;
    if (ci >= n) return;

    const unsigned long long* cb = cands + (size_t)b * CAND_CAP;
    const unsigned long long key = cb[ci];
    float v = __uint_as_float((unsigned int)(key >> 32));
    const int bk = bucket_of(v);
    const unsigned int seg0 = SA[b * NB + bk];
    const unsigned int len = hist[b * NB + bk];

    unsigned int r = 0;
#pragma unroll 4
    for (unsigned int j = 0; j < len; ++j) {
        r += (cb[seg0 + j] > key) ? 1u : 0u;
    }
    const unsigned int rank = seg0 + r;
    if (rank >= TOPK) return;

    const unsigned int idx = ~((unsigned int)(key & 0xFFFFFFFFull));
    const int ky = (int)(idx >> 11);
    const int kx = (int)(idx & (WW - 1));
    const float* img = scores + (size_t)b * NPIX;

    float patch[25];
#pragma unroll
    for (int dy = 0; dy < 5; ++dy) {
#pragma unroll
        for (int dx = 0; dx < 5; ++dx) {
            patch[dy * 5 + dx] = img[(size_t)(ky + dy - 2) * WW + (kx + dx - 2)];
        }
    }
    float mx = patch[0];
#pragma unroll
    for (int p = 1; p < 25; ++p) mx = fmaxf(mx, patch[p]);

    float e[25];
    float s = 0.0f, sx = 0.0f, sy = 0.0f;
#pragma unroll
    for (int p = 0; p < 25; ++p) {
        float ex = expf((patch[p] - mx) * 10.0f);
        e[p] = ex;
        s += ex;
        sx += ex * (float)(p % 5 - 2);
        sy += ex * (float)(p / 5 - 2);
    }
    const float xx = sx / s;
    const float yy = sy / s;

    float dsum = 0.0f;
#pragma unroll
    for (int p = 0; p < 25; ++p) {
        float ddx = ((float)(p % 5 - 2) - xx) * 0.5f;
        float ddy = ((float)(p / 5 - 2) - yy) * 0.5f;
        dsum += e[p] * (ddx * ddx + ddy * ddy);
    }
    const float disp = dsum / s;

    const float kxy_x = ((float)kx + xx) / (float)(WW - 1) * 2.0f - 1.0f;
    const float kxy_y = ((float)ky + yy) / (float)(HH - 1) * 2.0f - 1.0f;

    // bilinear resample (align_corners=True), same arithmetic path as reference
    const float px = (kxy_x + 1.0f) * 0.5f * (float)(WW - 1);
    const float py = (kxy_y + 1.0f) * 0.5f * (float)(HH - 1);
    int x0 = (int)floorf(px); x0 = x0 < 0 ? 0 : (x0 > WW - 1 ? WW - 1 : x0);
    int y0 = (int)floorf(py); y0 = y0 < 0 ? 0 : (y0 > HH - 1 ? HH - 1 : y0);
    int x1 = x0 + 1 > WW - 1 ? WW - 1 : x0 + 1;
    int y1 = y0 + 1 > HH - 1 ? HH - 1 : y0 + 1;
    const float wx = px - (float)x0;
    const float wy = py - (float)y0;
    const float v00 = img[(size_t)y0 * WW + x0];
    const float v01 = img[(size_t)y0 * WW + x1];
    const float v10 = img[(size_t)y1 * WW + x0];
    const float v11 = img[(size_t)y1 * WW + x1];
    const float ksc = v00 * (1.0f - wx) * (1.0f - wy) + v01 * wx * (1.0f - wy)
                    + v10 * (1.0f - wx) * wy + v11 * wx * wy;

    const size_t ok = (size_t)b * TOPK + rank;
    out[2 * ok]     = kxy_x;
    out[2 * ok + 1] = kxy_y;
    out[(size_t)BATCH * TOPK * 2 + ok] = ksc;
    out[(size_t)BATCH * TOPK * 3 + ok] = disp;
}

extern "C" void kernel_launch(void* const* d_in, const int* in_sizes, int n_in,
                              void* d_out, int out_size, void* d_ws, size_t ws_size,
                              hipStream_t stream) {
    const float* scores = (const float*)d_in[0];
    float* out = (float*)d_out;
    char* ws = (char*)d_ws;

    unsigned long long* peaks = (unsigned long long*)(ws + OFF_PEAKS);
    unsigned long long* cands = (unsigned long long*)(ws + OFF_CANDS);
    unsigned int* hist   = (unsigned int*)(ws + OFF_HIST);
    unsigned int* SA     = (unsigned int*)(ws + OFF_SA);
    unsigned int* fill   = (unsigned int*)(ws + OFF_FILL);
    unsigned int* pcount = (unsigned int*)(ws + OFF_PCOUNT);
    unsigned int* ncand  = (unsigned int*)(ws + OFF_NCAND);
    unsigned int* bstar  = (unsigned int*)(ws + OFF_BSTAR);

    // zero hist / SA / fill / counters in one memset
    hipMemsetAsync(ws + OFF_HIST, 0, (size_t)(OFF_END - OFF_HIST), stream);

    k_nms<<<dim3(WW / 1024, HH / 8, BATCH), 256, 0, stream>>>(scores, peaks, hist, pcount);
    k_scan<<<dim3(BATCH), 256, 0, stream>>>(hist, SA, ncand, bstar);
    k_filter<<<dim3(PEAK_CAP / 256, BATCH), 256, 0, stream>>>(peaks, pcount, bstar, SA, fill, cands);
    k_out<<<dim3(CAND_CAP / 256, BATCH), 256, 0, stream>>>(scores, cands, ncand, SA, hist, out);
}